// Round 7
// baseline (111.243 us; speedup 1.0000x reference)
//
#include <hip/hip_runtime.h>
#include <hip/hip_bf16.h>

typedef __attribute__((ext_vector_type(8))) short bf16x8;
typedef __attribute__((ext_vector_type(16))) float f32x16;
typedef __attribute__((ext_vector_type(4))) unsigned short u16x4;

#define TT 128
#define DD 256
#define BK 64
#define CP 1056          // chunk pitch: 1 KiB chunk + 32 B skew
#define PAN (16 * CP)    // panel bytes = 16896
#define BUFSZ (2 * PAN)  // A+B panels per buffer = 33792
#define PART (2 * BUFSZ) // partials offset = 67584
#define K2L 2.8853900817779268f   // 2 * log2(e):  exp(2x) = exp2(x*K2L)

__device__ __forceinline__ unsigned short f2bf(float f) {
  unsigned int x = __float_as_uint(f);
  x += 0x7fffu + ((x >> 16) & 1u);          // round-to-nearest-even
  return (unsigned short)(x >> 16);
}

__device__ __forceinline__ bf16x8 pack8(float4 lo, float4 hi) {
  bf16x8 v;
  v[0] = (short)f2bf(lo.x); v[1] = (short)f2bf(lo.y);
  v[2] = (short)f2bf(lo.z); v[3] = (short)f2bf(lo.w);
  v[4] = (short)f2bf(hi.x); v[5] = (short)f2bf(hi.y);
  v[6] = (short)f2bf(hi.z); v[7] = (short)f2bf(hi.w);
  return v;
}

// One-shot f32 -> bf16 preconversion of both feature tensors.
__global__ __launch_bounds__(256) void conv_kernel(
    const float* __restrict__ v, const float* __restrict__ w,
    unsigned short* __restrict__ vb, unsigned short* __restrict__ wb) {
  const int idx = blockIdx.x * 256 + threadIdx.x;   // float4 units
  float4 a = reinterpret_cast<const float4*>(v)[idx];
  float4 b = reinterpret_cast<const float4*>(w)[idx];
  u16x4 pa, pb;
  pa[0] = f2bf(a.x); pa[1] = f2bf(a.y); pa[2] = f2bf(a.z); pa[3] = f2bf(a.w);
  pb[0] = f2bf(b.x); pb[1] = f2bf(b.y); pb[2] = f2bf(b.z); pb[3] = f2bf(b.w);
  reinterpret_cast<u16x4*>(vb)[idx] = pa;
  reinterpret_cast<u16x4*>(wb)[idx] = pb;
}

// One workgroup (512 thr, 8 waves) per (i,j).  Dual-orientation 32x32x16
// MFMA GEMM, wave tile 64x64 (acc = 64 regs -> 4 waves/SIMD cap):
//   o=wid>>2 (0:S=video x wifi^T, 1:St=wifi x video^T), mg=row half, cg=col half.
// Panels chunk-skewed (pitch 1056B per 8-row chunk) to break the 4-way bank
// aliasing of 128B rows.  Pooling: reg-local max/exp + shfl32 merge + LDS
// half-merge (online-softmax merge, one barrier fewer than 3-pass).
template <bool PRE>
__global__ __launch_bounds__(512, 4) void pair_kernel(
    const float* __restrict__ videof, const float* __restrict__ wifif,
    const unsigned short* __restrict__ videob,
    const unsigned short* __restrict__ wifib,
    float* __restrict__ dense) {
  __shared__ __align__(16) char lds[73744];
  const int tid = threadIdx.x;
  const int bid = blockIdx.x;
  const int bi = bid >> 6, bj = bid & 63;
  const int wid = tid >> 6, l = tid & 63;
  const int l31 = l & 31;

  const int o  = wid >> 2;          // orientation
  const int mg = wid & 1;           // 64-row half of X
  const int cg = (wid >> 1) & 1;    // 64-col half of Y

  // ---- staging constants ----
  const char* vsrc = (const char*)videob + (size_t)bi * (TT * DD * 2);
  const char* wsrc = (const char*)wifib  + (size_t)bj * (TT * DD * 2);
  const int grow8 = l >> 3;                       // row within 8-row chunk
  const int gcb   = ((l & 7) ^ grow8) << 4;       // inverse-swizzled src byte
  // non-PRE fallback
  const int srow = tid >> 2;
  const int scb  = (tid & 3) * 32;
  const int sswz = (srow & 7) << 4;
  const int srbase = (srow >> 3) * CP + (srow & 7) * 128;

  f32x16 acc[2][2];
#pragma unroll
  for (int mi = 0; mi < 2; ++mi)
#pragma unroll
    for (int t = 0; t < 2; ++t)
#pragma unroll
      for (int r = 0; r < 16; ++r) acc[mi][t][r] = 0.f;

  const int apan = o ? PAN : 0;     // X panel (wifi when o=1)
  const int bpan = o ? 0 : PAN;     // Y panel
  const int xr    = (l31 & 7) << 4; // read-side swizzle
  const int khalf = (l >> 5) * 16;
  const int xrow  = mg * 64 + l31;
  const int ycol  = cg * 64 + l31;
  const int xbase = (xrow >> 3) * CP + (xrow & 7) * 128;
  const int ybase = (ycol >> 3) * CP + (ycol & 7) * 128;

#define STAGE_PRE(KP, BUF)                                                    \
  do {                                                                        \
    _Pragma("unroll") for (int k_ = 0; k_ < 4; ++k_) {                        \
      const int q_ = wid * 4 + k_;                                            \
      const int c_ = q_ & 15;                                                 \
      const char* s_ = ((q_ < 16) ? vsrc : wsrc) + (c_ * 8 + grow8) * 512 +   \
                       (KP) * 128 + gcb;                                      \
      char* d_ = lds + (BUF) * BUFSZ + ((q_ < 16) ? 0 : PAN) + c_ * CP;       \
      __builtin_amdgcn_global_load_lds((const void*)s_, (void*)d_, 16, 0, 0); \
    }                                                                         \
  } while (0)

#define STAGE_REG(KP, BUF)                                                    \
  do {                                                                        \
    const float* pa_ = videof + (size_t)bi * (TT * DD) + srow * DD +          \
                       (KP) * BK + (tid & 3) * 16;                            \
    const float* pb_ = wifif + (size_t)bj * (TT * DD) + srow * DD +           \
                       (KP) * BK + (tid & 3) * 16;                            \
    float4 a0_ = *(const float4*)(pa_);                                       \
    float4 a1_ = *(const float4*)(pa_ + 4);                                   \
    float4 a2_ = *(const float4*)(pa_ + 8);                                   \
    float4 a3_ = *(const float4*)(pa_ + 12);                                  \
    float4 b0_ = *(const float4*)(pb_);                                       \
    float4 b1_ = *(const float4*)(pb_ + 4);                                   \
    float4 b2_ = *(const float4*)(pb_ + 8);                                   \
    float4 b3_ = *(const float4*)(pb_ + 12);                                  \
    char* base_ = lds + (BUF) * BUFSZ;                                        \
    const int c0_ = srbase + ((scb) ^ sswz);                                  \
    const int c1_ = srbase + ((scb + 16) ^ sswz);                             \
    *(bf16x8*)(base_ + c0_)       = pack8(a0_, a1_);                          \
    *(bf16x8*)(base_ + c1_)       = pack8(a2_, a3_);                          \
    *(bf16x8*)(base_ + PAN + c0_) = pack8(b0_, b1_);                          \
    *(bf16x8*)(base_ + PAN + c1_) = pack8(b2_, b3_);                          \
  } while (0)

  if constexpr (PRE) STAGE_PRE(0, 0); else STAGE_REG(0, 0);
  __syncthreads();

  for (int kp = 0; kp < 4; ++kp) {
    const int bufoff = (kp & 1) * BUFSZ;
    if (kp < 3) {                       // prefetch next panel into other buf
      if constexpr (PRE) STAGE_PRE(kp + 1, (kp + 1) & 1);
      else STAGE_REG(kp + 1, (kp + 1) & 1);
    }
    const char* xb = lds + bufoff + apan + xbase;
    const char* yb = lds + bufoff + bpan + ybase;
#pragma unroll
    for (int ks = 0; ks < 4; ++ks) {
      const int off = (ks * 32 + khalf) ^ xr;
      bf16x8 ax0 = *(const bf16x8*)(xb + off);
      bf16x8 ax1 = *(const bf16x8*)(xb + 4 * CP + off);
      bf16x8 by0 = *(const bf16x8*)(yb + off);
      bf16x8 by1 = *(const bf16x8*)(yb + 4 * CP + off);
      acc[0][0] = __builtin_amdgcn_mfma_f32_32x32x16_bf16(ax0, by0, acc[0][0], 0, 0, 0);
      acc[0][1] = __builtin_amdgcn_mfma_f32_32x32x16_bf16(ax0, by1, acc[0][1], 0, 0, 0);
      acc[1][0] = __builtin_amdgcn_mfma_f32_32x32x16_bf16(ax1, by0, acc[1][0], 0, 0, 0);
      acc[1][1] = __builtin_amdgcn_mfma_f32_32x32x16_bf16(ax1, by1, acc[1][1], 0, 0, 0);
    }
    __syncthreads();                    // panel consumed + next one staged
  }

  // ---- pooling partials: PM/PS/PV [o][mg][128] f32 ----
  float* PM = (float*)(lds + PART);
  float* PS = PM + 512;
  float* PV = PM + 1024;
  float* Gb = PM + 1536;

  // per-column (of this wave's 64 cols): local max + exp-sums over 32 rows,
  // then softmax-merge with lane^32 (other interleaved 32 rows).
#pragma unroll
  for (int t = 0; t < 2; ++t) {
    float mx = acc[0][t][0];
#pragma unroll
    for (int r = 1; r < 16; ++r) mx = fmaxf(mx, acc[0][t][r]);
#pragma unroll
    for (int r = 0; r < 16; ++r) mx = fmaxf(mx, acc[1][t][r]);
    const float mxk = mx * K2L;
    float se = 0.f, sv = 0.f;
#pragma unroll
    for (int mi = 0; mi < 2; ++mi)
#pragma unroll
      for (int r = 0; r < 16; ++r) {
        const float v = acc[mi][t][r];
        const float e = exp2f(fmaf(v, K2L, -mxk));
        se += e;
        sv = fmaf(e, v, sv);
      }
    const float om = __shfl_xor(mx, 32);
    const float os = __shfl_xor(se, 32);
    const float ov = __shfl_xor(sv, 32);
    const float M  = fmaxf(mx, om);
    const float f1 = exp2f((mx - M) * K2L);
    const float f2 = exp2f((om - M) * K2L);
    se = fmaf(se, f1, os * f2);
    sv = fmaf(sv, f1, ov * f2);
    if (l < 32) {
      const int idx = o * 256 + mg * 128 + cg * 64 + t * 32 + l;
      PM[idx] = M; PS[idx] = se; PV[idx] = sv;
    }
  }
  __syncthreads();

  // merge the two 64-row halves per column -> soft_sim value, in place (PM row 0)
  if (tid < 256) {
    const int o2 = tid >> 7, c = tid & 127;
    const int i0 = o2 * 256 + c, i1 = i0 + 128;
    const float m0 = PM[i0], m1 = PM[i1];
    const float M  = fmaxf(m0, m1);
    const float f0 = exp2f((m0 - M) * K2L);
    const float f1 = exp2f((m1 - M) * K2L);
    const float s  = fmaf(PS[i0], f0, PS[i1] * f1);
    const float v  = fmaf(PV[i0], f0, PV[i1] * f1);
    PM[i0] = v / s;
  }
  __syncthreads();

  // frame-level softmax pooling -> scalars
  // wave 0: v2w (cols = video frames -> o=1 partials); wave 1: w2v (o=0)
  if (wid < 2) {
    const float* RS = PM + (wid == 0 ? 256 : 0);
    float a0 = RS[l], a1 = RS[64 + l];
    float mx = fmaxf(a0, a1);
#pragma unroll
    for (int s = 1; s < 64; s <<= 1) mx = fmaxf(mx, __shfl_xor(mx, s));
    float e0 = exp2f((a0 - mx) * K2L), e1 = exp2f((a1 - mx) * K2L);
    float se = e0 + e1, sev = fmaf(e0, a0, e1 * a1);
#pragma unroll
    for (int s = 1; s < 64; s <<= 1) { se += __shfl_xor(se, s); sev += __shfl_xor(sev, s); }
    if (l == 0) Gb[wid] = sev / se;
  }
  __syncthreads();
  if (tid == 0) dense[bid] = 0.5f * (Gb[0] + Gb[1]);
}

// Label-smoothed symmetric CE over the 64x64 dense-similarity matrix. f32 out.
__global__ __launch_bounds__(64) void loss_kernel(
    const float* __restrict__ dense, const float* __restrict__ scalep,
    float* __restrict__ out) {
  const int i = threadIdx.x;
  const float sc = fminf(scalep[0], 40.0f);
  float mxr = -3.4e38f, mxc = -3.4e38f;
  for (int j = 0; j < 64; ++j) {
    mxr = fmaxf(mxr, sc * dense[i * 64 + j]);
    mxc = fmaxf(mxc, sc * dense[j * 64 + i]);
  }
  float ser = 0.f, sec = 0.f, slr = 0.f, slc = 0.f;
  for (int j = 0; j < 64; ++j) {
    float zr = sc * dense[i * 64 + j];
    float zc = sc * dense[j * 64 + i];
    ser += __expf(zr - mxr); sec += __expf(zc - mxc);
    slr += zr;               slc += zc;
  }
  const float lser = mxr + logf(ser);
  const float lsec = mxc + logf(sec);
  const float zd = sc * dense[i * 65];
  float lv = lser - 0.9f * zd - 0.1f * (slr * (1.0f / 64.0f));
  float lw = lsec - 0.9f * zd - 0.1f * (slc * (1.0f / 64.0f));
  float t = 0.5f * (lv + lw);
#pragma unroll
  for (int s = 1; s < 64; s <<= 1) t += __shfl_xor(t, s);
  if (i == 0) out[0] = t * (1.0f / 64.0f);
}

extern "C" void kernel_launch(void* const* d_in, const int* in_sizes, int n_in,
                              void* d_out, int out_size, void* d_ws, size_t ws_size,
                              hipStream_t stream) {
  (void)in_sizes; (void)n_in; (void)out_size;
  const float* video = (const float*)d_in[0];
  const float* wifi  = (const float*)d_in[1];
  const float* scale = (const float*)d_in[2];
  float* dense = (float*)d_ws;                                   // 16 KiB
  unsigned short* vb = (unsigned short*)((char*)d_ws + 16384);   // 4 MiB
  unsigned short* wb = vb + 64 * TT * DD;                        // 4 MiB

  const bool pre = ws_size >= (size_t)16384 + 2u * 64 * TT * DD * 2;
  if (pre) {
    hipLaunchKernelGGL(conv_kernel, dim3(2048), dim3(256), 0, stream,
                       video, wifi, vb, wb);
    hipLaunchKernelGGL((pair_kernel<true>), dim3(64 * 64), dim3(512), 0, stream,
                       video, wifi, vb, wb, dense);
  } else {
    hipLaunchKernelGGL((pair_kernel<false>), dim3(64 * 64), dim3(512), 0, stream,
                       video, wifi, vb, wb, dense);
  }
  hipLaunchKernelGGL(loss_kernel, dim3(1), dim3(64), 0, stream,
                     dense, scale, (float*)d_out);
}